// Round 5
// baseline (409.065 us; speedup 1.0000x reference)
//
#include <hip/hip_runtime.h>
#include <hip/hip_bf16.h>

constexpr int NN   = 10000;
constexpr int NE   = 160000;
constexpr int INC  = 256;
constexpr int H    = 8;
constexpr int D1   = 1024;     // 8 heads x 128
constexpr int OUTC = 32;
constexpr int MPAD = 10112;    // 79 * 128
constexpr float NEG_SLOPE = 0.2f;

typedef __attribute__((ext_vector_type(8))) short bf16x8;
typedef __attribute__((ext_vector_type(4))) float f32x4;

__device__ __forceinline__ unsigned short f2b(float f) {
  unsigned u = __float_as_uint(f);
  unsigned r = (u + 0x7fffu + ((u >> 16) & 1u)) >> 16;
  return (unsigned short)r;
}
__device__ __forceinline__ float b2f_lo(unsigned u) { return __uint_as_float(u << 16); }
__device__ __forceinline__ float b2f_hi(unsigned u) { return __uint_as_float(u & 0xffff0000u); }
__device__ __forceinline__ float lrelu(float a) { return fmaxf(a, 0.f) + NEG_SLOPE * fminf(a, 0.f); }

// ---------------- CSR build ----------------
__global__ void deg_hist(const int* __restrict__ dst, int* __restrict__ deg) {
  int e = blockIdx.x * 256 + threadIdx.x;
  if (e < NE) atomicAdd(&deg[dst[e]], 1);
}
// exclusive scan -> rowptr[NN+1], also seeds cursor
__global__ __launch_bounds__(64) void scan_rowptr(const int* __restrict__ deg,
                                                  int* __restrict__ rowptr,
                                                  int* __restrict__ cursor) {
  int lane = threadIdx.x;
  int carry = 0;
  for (int base = 0; base < NN; base += 64) {
    int i = base + lane;
    int v = (i < NN) ? deg[i] : 0;
    int s = v;
#pragma unroll
    for (int off = 1; off < 64; off <<= 1) {
      int t = __shfl_up(s, off);
      if (lane >= off) s += t;
    }
    if (i < NN) { rowptr[i] = carry + s - v; cursor[i] = carry + s - v; }
    carry += __shfl(s, 63);
  }
  if (lane == 0) rowptr[NN] = carry;
}
__global__ void csr_fill(const int* __restrict__ dst, int* __restrict__ cursor,
                         int* __restrict__ csr_e) {
  int e = blockIdx.x * 256 + threadIdx.x;
  if (e >= NE) return;
  int pos = atomicAdd(&cursor[dst[e]], 1);
  csr_e[pos] = e;
}

// ---------------- conversions ----------------
__global__ void cvt_x(const float* __restrict__ x, short* __restrict__ Xb) {
  int i = blockIdx.x * 256 + threadIdx.x;
  int base = i * 4;
  if (base >= MPAD * INC) return;
  ushort4 o;
  if (base < NN * INC) {
    float4 v = *(const float4*)(x + base);
    o.x = f2b(v.x); o.y = f2b(v.y); o.z = f2b(v.z); o.w = f2b(v.w);
  } else {
    o.x = o.y = o.z = o.w = 0;
  }
  *(ushort4*)(Xb + base) = o;
}

// dual-source transpose+convert: dst rows [0,NsrcHalf) from srcA, [NsrcHalf,2*NsrcHalf) from srcB
// src layout [K][NsrcHalf] fp32 -> dst [2*NsrcHalf][K] bf16. grid (2*NsrcHalf/32, K/32)
__global__ __launch_bounds__(256) void transpose_cvt_dual(const float* __restrict__ srcA,
                                                          const float* __restrict__ srcB,
                                                          short* __restrict__ dst,
                                                          int K, int NsrcHalf) {
  __shared__ float tile[32][33];
  int tx = threadIdx.x & 31, ty = threadIdx.x >> 5;
  int nb = blockIdx.x * 32, kb = blockIdx.y * 32;
  const float* src = srcA;
  int nloc = nb;
  if (nb >= NsrcHalf) { src = srcB; nloc = nb - NsrcHalf; }
#pragma unroll
  for (int i = 0; i < 4; i++)
    tile[ty + i * 8][tx] = src[(size_t)(kb + ty + i * 8) * NsrcHalf + nloc + tx];
  __syncthreads();
#pragma unroll
  for (int i = 0; i < 4; i++)
    dst[(size_t)(nb + ty + i * 8) * K + kb + tx] = (short)f2b(tile[tx][ty + i * 8]);
}

// ---------------- bf16 MFMA GEMM ----------------
template<int BF16OUT>
__global__ __launch_bounds__(256) void gemm_bf16(const short* __restrict__ Xb,
                                                 const short* __restrict__ Wt,
                                                 void* __restrict__ Cout,
                                                 int M, int K, int ldc, int nvalid) {
  __shared__ short As[4096];
  __shared__ short Bs[4096];
  const int t = threadIdx.x;
  const int lane = t & 63;
  const int w = t >> 6;
  const int wr = w >> 1, wc = w & 1;
  const int row0 = blockIdx.y * 128;
  const int col0 = blockIdx.x * 128;
  const int r_st = t & 127;
  const int kc_st = t >> 7;
  f32x4 acc[4][4] = {};
  for (int k0 = 0; k0 < K; k0 += 32) {
    bf16x8 va0 = *(const bf16x8*)(Xb + (size_t)(row0 + r_st) * K + k0 + kc_st * 8);
    bf16x8 va1 = *(const bf16x8*)(Xb + (size_t)(row0 + r_st) * K + k0 + (kc_st + 2) * 8);
    bf16x8 vb0 = *(const bf16x8*)(Wt + (size_t)(col0 + r_st) * K + k0 + kc_st * 8);
    bf16x8 vb1 = *(const bf16x8*)(Wt + (size_t)(col0 + r_st) * K + k0 + (kc_st + 2) * 8);
    __syncthreads();
    *(bf16x8*)&As[(kc_st)     * 1024 + r_st * 8] = va0;
    *(bf16x8*)&As[(kc_st + 2) * 1024 + r_st * 8] = va1;
    *(bf16x8*)&Bs[(kc_st)     * 1024 + r_st * 8] = vb0;
    *(bf16x8*)&Bs[(kc_st + 2) * 1024 + r_st * 8] = vb1;
    __syncthreads();
    bf16x8 af[4], bfr[4];
#pragma unroll
    for (int i = 0; i < 4; i++)
      af[i] = *(const bf16x8*)&As[(lane >> 4) * 1024 + (wr * 64 + i * 16 + (lane & 15)) * 8];
#pragma unroll
    for (int j = 0; j < 4; j++)
      bfr[j] = *(const bf16x8*)&Bs[(lane >> 4) * 1024 + (wc * 64 + j * 16 + (lane & 15)) * 8];
#pragma unroll
    for (int i = 0; i < 4; i++)
#pragma unroll
      for (int j = 0; j < 4; j++)
        acc[i][j] = __builtin_amdgcn_mfma_f32_16x16x32_bf16(af[i], bfr[j], acc[i][j], 0, 0, 0);
  }
#pragma unroll
  for (int i = 0; i < 4; i++) {
    int rb = row0 + wr * 64 + i * 16 + (lane >> 4) * 4;
#pragma unroll
    for (int reg = 0; reg < 4; reg++) {
      int gr = rb + reg;
      if (gr < M) {
#pragma unroll
        for (int j = 0; j < 4; j++) {
          int gc = col0 + wc * 64 + j * 16 + (lane & 15);
          if (gc < nvalid) {
            if (BF16OUT) ((short*)Cout)[(size_t)gr * ldc + gc] = (short)f2b(acc[i][j][reg]);
            else         ((float*)Cout)[(size_t)gr * ldc + gc] = acc[i][j][reg];
          }
        }
      }
    }
  }
}

// ---------------- per-node att dot-products: alar[n][0..7]=att.xl, [8..15]=att.xr ----------------
// block per node; thread t owns 8 channels of the 2048-wide xlr row; 16-lane tree reduce.
__global__ __launch_bounds__(256) void prep_alar(const short* __restrict__ xlr,
                                                 const float* __restrict__ att,
                                                 float* __restrict__ alar) {
  const int n = blockIdx.x;
  const int t = threadIdx.x;
  const int ch = t * 8;
  const uint4 v = *(const uint4*)(xlr + (size_t)n * 2048 + ch);
  const int ac = ch & 1023;
  const float4 a0 = *(const float4*)(att + ac);
  const float4 a1 = *(const float4*)(att + ac + 4);
  float s = b2f_lo(v.x) * a0.x + b2f_hi(v.x) * a0.y
          + b2f_lo(v.y) * a0.z + b2f_hi(v.y) * a0.w
          + b2f_lo(v.z) * a1.x + b2f_hi(v.z) * a1.y
          + b2f_lo(v.w) * a1.z + b2f_hi(v.w) * a1.w;
#pragma unroll
  for (int off = 1; off < 16; off <<= 1) s += __shfl_xor(s, off);
  if ((t & 15) == 0) alar[n * 16 + (t >> 4)] = s;
}

// ---------------- fused layer-1 attention (register-stash, abs-decomposed scores) ----------------
// block per dst node; thread t owns channels 4t..4t+3 (head = t>>5).
// score e = 0.6*(al[s,h]+ar[d,h]) + 0.4*sum_c att[c]*|xl[s,c]+xr[d,c]|
__global__ __launch_bounds__(256) void attn1(const int* __restrict__ rowptr, const int* __restrict__ csr_e,
                                             const int* __restrict__ src, const short* __restrict__ xlr,
                                             const float* __restrict__ att, const float* __restrict__ alar,
                                             const float* __restrict__ b1, short* __restrict__ h1b) {
  constexpr int CH = 8;
  __shared__ float sc[CH][8];
  __shared__ int   sarr[CH];
  const int d = blockIdx.x;
  const int t = threadIdx.x;
  const int h = t >> 5;
  uint2 xru = *(const uint2*)(xlr + (size_t)d * 2048 + 1024 + 4 * t);
  const float xr0 = b2f_lo(xru.x), xr1 = b2f_hi(xru.x), xr2v = b2f_lo(xru.y), xr3 = b2f_hi(xru.y);
  const float4 at = *(const float4*)(att + 4 * t);
  const float ar_h = alar[d * 16 + 8 + h];
  float m = -3.4e38f, den = 0.f;
  float4 acc = make_float4(0.f, 0.f, 0.f, 0.f);
  const int jb = rowptr[d], je = rowptr[d + 1];
  for (int j0 = jb; j0 < je; j0 += CH) {
    const int rem = je - j0;
    __syncthreads();                       // prev chunk done with sarr/sc
    if (t < CH && t < rem) sarr[t] = src[csr_e[j0 + t]];
    __syncthreads();
    float4 xv[CH];
#pragma unroll
    for (int k = 0; k < CH; k++) {
      if (k < rem) {
        uint2 v = *(const uint2*)(xlr + (size_t)sarr[k] * 2048 + 4 * t);
        xv[k] = make_float4(b2f_lo(v.x), b2f_hi(v.x), b2f_lo(v.y), b2f_hi(v.y));
      }
    }
#pragma unroll
    for (int k = 0; k < CH; k++) {
      if (k < rem) {
        float p = fabsf(xv[k].x + xr0) * at.x;
        p += fabsf(xv[k].y + xr1) * at.y;
        p += fabsf(xv[k].z + xr2v) * at.z;
        p += fabsf(xv[k].w + xr3) * at.w;
#pragma unroll
        for (int off = 16; off > 0; off >>= 1) p += __shfl_xor(p, off);
        if ((t & 31) == 0)
          sc[k][h] = 0.4f * p + 0.6f * (alar[sarr[k] * 16 + h] + ar_h);
      }
    }
    __syncthreads();
    float scv[CH];
    float cmax = -3.4e38f;
#pragma unroll
    for (int k = 0; k < CH; k++)
      if (k < rem) { scv[k] = sc[k][h]; cmax = fmaxf(cmax, scv[k]); }
    float newm = fmaxf(m, cmax);
    float r = __expf(m - newm);            // 0 on first chunk
    acc.x *= r; acc.y *= r; acc.z *= r; acc.w *= r; den *= r;
    m = newm;
#pragma unroll
    for (int k = 0; k < CH; k++) {
      if (k < rem) {
        float w = __expf(scv[k] - m);
        den += w;
        acc.x += w * xv[k].x; acc.y += w * xv[k].y;
        acc.z += w * xv[k].z; acc.w += w * xv[k].w;
      }
    }
  }
  float inv = 1.f / (den + 1e-16f);
  float4 b = *(const float4*)(b1 + 4 * t);
  float o0 = acc.x * inv + b.x, o1 = acc.y * inv + b.y;
  float o2 = acc.z * inv + b.z, o3 = acc.w * inv + b.w;
  o0 = o0 > 0.f ? o0 : expm1f(o0);
  o1 = o1 > 0.f ? o1 : expm1f(o1);
  o2 = o2 > 0.f ? o2 : expm1f(o2);
  o3 = o3 > 0.f ? o3 : expm1f(o3);
  ushort4 o;
  o.x = f2b(o0); o.y = f2b(o1); o.z = f2b(o2); o.w = f2b(o3);
  *(ushort4*)(h1b + (size_t)d * 1024 + 4 * t) = o;
}

// ---------------- fused layer-2: scores + online softmax + agg + bias + log_softmax ----------------
__global__ __launch_bounds__(256) void attn2(const int* __restrict__ rowptr, const int* __restrict__ csr_e,
                                             const int* __restrict__ src, const float* __restrict__ xlr2,
                                             const float* __restrict__ att2, const float* __restrict__ b2,
                                             float* __restrict__ out) {
  const int t = threadIdx.x;
  const int d = blockIdx.x * 8 + (t >> 5);
  const int c = t & 31;
  if (d >= NN) return;
  const float xr = xlr2[d * 64 + 32 + c];
  const float a2 = att2[c];
  float m = -3.4e38f, den = 0.f, acc = 0.f;
  const int jb = rowptr[d], je = rowptr[d + 1];
  for (int j = jb; j < je; j++) {
    int e = csr_e[j];
    int s = src[e];
    float xv = xlr2[s * 64 + c];
    float p = a2 * lrelu(xv + xr);
#pragma unroll
    for (int off = 16; off > 0; off >>= 1) p += __shfl_xor(p, off);
    if (p > m) {
      float r = __expf(m - p);
      acc *= r; den *= r; m = p;
    }
    float w = __expf(p - m);
    den += w;
    acc += w * xv;
  }
  float v = acc / (den + 1e-16f) + b2[c];
  float mx = v;
#pragma unroll
  for (int off = 16; off > 0; off >>= 1) mx = fmaxf(mx, __shfl_xor(mx, off));
  float ex = __expf(v - mx);
  float sum = ex;
#pragma unroll
  for (int off = 16; off > 0; off >>= 1) sum += __shfl_xor(sum, off);
  out[d * 32 + c] = v - mx - logf(sum);
}

extern "C" void kernel_launch(void* const* d_in, const int* in_sizes, int n_in,
                              void* d_out, int out_size, void* d_ws, size_t ws_size,
                              hipStream_t stream) {
  const float* x    = (const float*)d_in[0];
  const int*   ei   = (const int*)d_in[1];
  const float* W1l  = (const float*)d_in[2];
  const float* W1r  = (const float*)d_in[3];
  const float* att1 = (const float*)d_in[4];
  const float* b1   = (const float*)d_in[5];
  const float* W2l  = (const float*)d_in[6];
  const float* W2r  = (const float*)d_in[7];
  const float* att2 = (const float*)d_in[8];
  const float* b2   = (const float*)d_in[9];
  float* out = (float*)d_out;

  // workspace layout
  short* Xb   = (short*)d_ws;                        // MPAD*256
  short* Wt1  = Xb + (size_t)MPAD * 256;             // 2048*256
  short* Wt2  = Wt1 + (size_t)2048 * 256;            // 128*1024
  short* xlr  = Wt2 + (size_t)128 * 1024;            // NN*2048 bf16 (xl | xr)
  short* h1b  = xlr + (size_t)NN * 2048;             // MPAD*1024 bf16
  float* xlr2 = (float*)(h1b + (size_t)MPAD * 1024); // NN*64
  float* alar = xlr2 + (size_t)NN * 64;              // NN*16
  int* deg    = (int*)(alar + (size_t)NN * 16);      // NN
  int* rowptr = deg + NN;                            // NN+1
  int* cursor = rowptr + NN + 1;                     // NN
  int* csr_e  = cursor + NN;                         // NE

  const int* src = ei;
  const int* dst = ei + NE;

  // CSR build
  hipMemsetAsync(deg, 0, NN * sizeof(int), stream);
  deg_hist<<<(NE + 255) / 256, 256, 0, stream>>>(dst, deg);
  scan_rowptr<<<1, 64, 0, stream>>>(deg, rowptr, cursor);
  csr_fill<<<(NE + 255) / 256, 256, 0, stream>>>(dst, cursor, csr_e);

  // conversions
  cvt_x<<<(MPAD * 256 / 4 + 255) / 256, 256, 0, stream>>>(x, Xb);
  {
    dim3 g(2048 / 32, 256 / 32);
    transpose_cvt_dual<<<g, 256, 0, stream>>>(W1l, W1r, Wt1, 256, 1024);
  }
  {
    dim3 g(64 / 32, 1024 / 32);
    transpose_cvt_dual<<<g, 256, 0, stream>>>(W2l, W2r, Wt2, 1024, 32);
    hipMemsetAsync(Wt2 + (size_t)64 * 1024, 0, (size_t)64 * 1024 * sizeof(short), stream);
  }

  // layer-1 GEMM -> xlr bf16 [NN][2048]
  {
    dim3 g(2048 / 128, MPAD / 128);
    gemm_bf16<1><<<g, 256, 0, stream>>>(Xb, Wt1, xlr, NN, 256, 2048, 2048);
  }

  // per-node att dots for the separable part of the score
  prep_alar<<<NN, 256, 0, stream>>>(xlr, att1, alar);

  // fused layer-1 attention
  attn1<<<NN, 256, 0, stream>>>(rowptr, csr_e, src, xlr, att1, alar, b1, h1b);

  // layer-2 GEMM -> xlr2 fp32 [NN][64]
  {
    dim3 g(1, MPAD / 128);
    gemm_bf16<0><<<g, 256, 0, stream>>>(h1b, Wt2, xlr2, NN, 1024, 64, 64);
  }

  // fused layer-2 attention + log_softmax
  attn2<<<(NN + 7) / 8, 256, 0, stream>>>(rowptr, csr_e, src, xlr2, att2, b2, out);
}